// Round 19
// baseline (5098.651 us; speedup 1.0000x reference)
//
#include <hip/hip_runtime.h>
#include <math.h>

#define B_ 16
#define T_ 64
#define N_ 512
#define H_ 128
#define P_ 12
#define NH 65536  // N_*H_

// ---------------------------------------------------------------------------
// Lx[b,t,m] = sum_n L[m,n] * x[b,t,n]   (L symmetric)
// ---------------------------------------------------------------------------
__global__ __launch_bounds__(512) void lx_kernel(const float* __restrict__ x,
                                                 const float* __restrict__ L,
                                                 float* __restrict__ Lx) {
    __shared__ __align__(16) float xs[2][N_];
    const int r0 = blockIdx.x * 2;
    const int tid = threadIdx.x;
    for (int j = 0; j < 2; ++j)
        xs[j][tid] = x[(size_t)(r0 + j) * N_ + tid];
    __syncthreads();
    float a0 = 0.f, a1 = 0.f;
    const int m = tid;
#pragma unroll 8
    for (int n = 0; n < N_; ++n) {
        float lv = L[(size_t)n * N_ + m];
        a0 += xs[0][n] * lv;
        a1 += xs[1][n] * lv;
    }
    Lx[(size_t)(r0 + 0) * N_ + m] = a0;
    Lx[(size_t)(r0 + 1) * N_ + m] = a1;
}

#define FMA4(dst, a, hv)                                                      \
    dst[0] += (a) * (hv).x; dst[1] += (a) * (hv).y;                           \
    dst[2] += (a) * (hv).z; dst[3] += (a) * (hv).w;

// ===========================================================================
// gc1y — R27: R25's slim 8-row-tile body VERBATIM with PLAIN
// __launch_bounds__(512) — no min-waves hint.  R25/R26 proved the hint
// starves the allocator (VGPR 32/40 + spill); but the slim body (half of
// R21's accumulators, which compiles to 64 VGPR unbounded) should land
// naturally at <=64 VGPR.  At <=64 VGPR the HW allows 8 waves/SIMD, and
// 36.3KB LDS allows 4 blocks/CU -> grid 1024 gives 32 waves/CU = 8/SIMD
// WITHOUT forcing.  Mechanism evidence: R25's spilling variant still hit
// VALUBusy 64% — the only break of the session's 43-45% wall.
// Numerics already verified: R25 passed (absmax 4.768e-7).
// Tripwires: VGPR>=100 or WRITE>>8.2MB = spill; dur>=44us = theory dead ->
// re-submit R21 (3551us verified) as final next round.
// ===========================================================================
__global__ __launch_bounds__(512) void gc1y_kernel(
    const float* __restrict__ L, const float* __restrict__ Hprev,
    const float* __restrict__ Lx, const float* __restrict__ W1,
    const float* __restrict__ b1, const float* __restrict__ W2,
    float* __restrict__ Y, float* __restrict__ u, int t) {
    __shared__ __align__(16) union Buf {
        float Ht[2][32][H_];                              // 32768 B
        struct {
            float R[16][132];   //  8448 B
            float Zb[8][132];   //  4224 B
            float Wt[16][260];  // 16640 B  -> 29312 B
        } s;
    } bb;
    __shared__ __align__(16) float Lt[2][32][14];         // 3584 B -> 36352 B

    const int tid = threadIdx.x;
    const int b = blockIdx.x & 15;         // XCD-locality decode
    const int mt = blockIdx.x >> 4;        // 0..63
    const bool isR = (mt & 1) == 0;        // interleave r/u across CUs
    const int m0 = (mt >> 1) * 8 + (isR ? 0 : 256);   // Z rows m0..m0+7
    const float* __restrict__ Hb = Hprev + (size_t)b * NH;

    const int hrow = tid >> 5, hcol = (tid & 31) * 4;

    {
        *(float4*)&bb.Ht[0][hrow][hcol] =
            *(const float4*)&Hb[(size_t)hrow * H_ + hcol];
        *(float4*)&bb.Ht[0][hrow + 16][hcol] =
            *(const float4*)&Hb[(size_t)(hrow + 16) * H_ + hcol];
        if (tid < 256)
            Lt[0][tid & 31][tid >> 5] =
                L[(size_t)(m0 + (tid >> 5)) * N_ + (tid & 31)];
    }
    __syncthreads();

    const int g = tid >> 6;
    const int l = tid & 63;
    const int ty = l >> 4;
    const int tx = l & 15;
    const int ma0 = ty * 2;                // rows ma0, ma0+1 (of 8)
    const int ca0 = tx * 4, cb0 = 64 + tx * 4;

    float acc[2][2][4] = {};

    for (int kc = 0; kc < 16; ++kc) {
        const int bi = kc & 1, bj = bi ^ 1;
        float4 p0, p1;
        float pl;
        if (kc < 15) {
            const size_t kb = (size_t)(kc + 1) * 32;
            p0 = *(const float4*)&Hb[(kb + hrow) * H_ + hcol];
            p1 = *(const float4*)&Hb[(kb + hrow + 16) * H_ + hcol];
            if (tid < 256)
                pl = L[(size_t)(m0 + (tid >> 5)) * N_ + kb + (tid & 31)];
        }
#pragma unroll
        for (int kk = 0; kk < 4; ++kk) {
            const int k = g * 4 + kk;
            const float2 la = *(const float2*)&Lt[bi][k][ma0];
            const float4 h0 = *(const float4*)&bb.Ht[bi][k][ca0];
            const float4 h1 = *(const float4*)&bb.Ht[bi][k][cb0];
            FMA4(acc[0][0], la.x, h0) FMA4(acc[0][1], la.x, h1)
            FMA4(acc[1][0], la.y, h0) FMA4(acc[1][1], la.y, h1)
        }
        if (kc < 15) {
            *(float4*)&bb.Ht[bj][hrow][hcol] = p0;
            *(float4*)&bb.Ht[bj][hrow + 16][hcol] = p1;
            if (tid < 256)
                Lt[bj][tid & 31][tid >> 5] = pl;
        }
        __syncthreads();
    }

    for (int r = 0; r < 8; ++r) {
        if (g == r) {
#pragma unroll
            for (int i = 0; i < 2; ++i) {
#pragma unroll
                for (int v = 0; v < 2; ++v) {
                    const int c = v ? cb0 : ca0;
                    float4* zp = (float4*)&bb.s.Zb[ma0 + i][c];
                    if (r == 0) {
                        *zp = make_float4(acc[i][v][0], acc[i][v][1],
                                          acc[i][v][2], acc[i][v][3]);
                    } else {
                        float4 z = *zp;
                        *zp = make_float4(z.x + acc[i][v][0], z.y + acc[i][v][1],
                                          z.z + acc[i][v][2], z.w + acc[i][v][3]);
                    }
                }
            }
        }
        __syncthreads();
    }

    // ---- phase 2: ru = Zb @ W1[1:]  (wave-sliced cols; Wt staged per chunk)
    const int wv8 = tid >> 6;              // wave 0..7
    const int lr = l >> 3;                 // row 0..7
    const int lc = wv8 * 32 + (l & 7) * 4; // col 0..252
    const int wr = tid >> 5, wc = (tid & 31) * 4;
    float a2[4] = {};

#pragma unroll 1
    for (int ck = 0; ck < 8; ++ck) {
        *(float4*)&bb.s.Wt[wr][wc] =
            *(const float4*)&W1[(size_t)(1 + ck * 16 + wr) * 256 + wc];
        *(float4*)&bb.s.Wt[wr][wc + 128] =
            *(const float4*)&W1[(size_t)(1 + ck * 16 + wr) * 256 + wc + 128];
        __syncthreads();
#pragma unroll
        for (int ch4 = 0; ch4 < 4; ++ch4) {
            const int cc = ck * 16 + ch4 * 4;
            const float4 zv = *(const float4*)&bb.s.Zb[lr][cc];
            const float4 w0v = *(const float4*)&bb.s.Wt[ch4 * 4 + 0][lc];
            const float4 w1v = *(const float4*)&bb.s.Wt[ch4 * 4 + 1][lc];
            const float4 w2v = *(const float4*)&bb.s.Wt[ch4 * 4 + 2][lc];
            const float4 w3v = *(const float4*)&bb.s.Wt[ch4 * 4 + 3][lc];
            a2[0] += zv.x * w0v.x + zv.y * w1v.x + zv.z * w2v.x + zv.w * w3v.x;
            a2[1] += zv.x * w0v.y + zv.y * w1v.y + zv.z * w2v.y + zv.w * w3v.y;
            a2[2] += zv.x * w0v.z + zv.y * w1v.z + zv.z * w2v.z + zv.w * w3v.z;
            a2[3] += zv.x * w0v.w + zv.y * w1v.w + zv.z * w2v.w + zv.w * w3v.w;
        }
        __syncthreads();
    }

    const float4 w0r = *(const float4*)&W1[lc];
    const float4 bbv = *(const float4*)&b1[lc];
    const float lx = Lx[((size_t)b * T_ + t) * N_ + m0 + lr];

    float v0 = a2[0] + lx * w0r.x + bbv.x;
    float v1 = a2[1] + lx * w0r.y + bbv.y;
    float v2 = a2[2] + lx * w0r.z + bbv.z;
    float v3 = a2[3] + lx * w0r.w + bbv.w;
    float s0 = 1.f / (1.f + expf(-v0));
    float s1 = 1.f / (1.f + expf(-v1));
    float s2 = 1.f / (1.f + expf(-v2));
    float s3 = 1.f / (1.f + expf(-v3));

    if (isR) {
        // rh = s * Hprev -> R (flat (m0+lr)*256+lc -> H row 2(m0+lr)+(lc>>7))
        const int fl = (m0 + lr) * 256 + lc;
        const float4 hv = *(const float4*)&Hb[fl];
        *(float4*)&bb.s.R[2 * lr + (lc >> 7)][lc & 127] =
            make_float4(s0 * hv.x, s1 * hv.y, s2 * hv.z, s3 * hv.w);
        __syncthreads();

        // ---- phase 3: Y rows 2m0..2m0+15 = R @ W2[1:]
        const int pr = l >> 2;                 // 0..15
        const int pc = wv8 * 16 + (l & 3) * 4; // col 0..124
        float a3[4] = {};
#pragma unroll 1
        for (int ck = 0; ck < 8; ++ck) {
            *(float4*)&bb.s.Wt[wr][wc] =
                *(const float4*)&W2[(size_t)(1 + ck * 16 + wr) * H_ + wc];
            __syncthreads();
#pragma unroll
            for (int ch4 = 0; ch4 < 4; ++ch4) {
                const int cc = ck * 16 + ch4 * 4;
                const float4 z0 = *(const float4*)&bb.s.R[pr][cc];
                const float4 w0 = *(const float4*)&bb.s.Wt[ch4 * 4 + 0][pc];
                const float4 w1 = *(const float4*)&bb.s.Wt[ch4 * 4 + 1][pc];
                const float4 w2 = *(const float4*)&bb.s.Wt[ch4 * 4 + 2][pc];
                const float4 w3 = *(const float4*)&bb.s.Wt[ch4 * 4 + 3][pc];
                a3[0] += z0.x * w0.x + z0.y * w1.x + z0.z * w2.x + z0.w * w3.x;
                a3[1] += z0.x * w0.y + z0.y * w1.y + z0.z * w2.y + z0.w * w3.y;
                a3[2] += z0.x * w0.z + z0.y * w1.z + z0.z * w2.z + z0.w * w3.z;
                a3[3] += z0.x * w0.w + z0.y * w1.w + z0.z * w2.w + z0.w * w3.w;
            }
            __syncthreads();
        }
        float* __restrict__ Yb = Y + (size_t)b * NH;
        *(float4*)&Yb[(size_t)(2 * m0 + pr) * H_ + pc] =
            make_float4(a3[0], a3[1], a3[2], a3[3]);
    } else {
        // u-half: flat (m0+lr-256)*256+lc == H-layout linear
        float* __restrict__ uB = u + (size_t)b * NH;
        const int fl = (m0 + lr - 256) * 256 + lc;
        *(float4*)&uB[fl] = make_float4(s0, s1, s2, s3);
    }
}

// ===========================================================================
// gcz_kernel — R18 version VERBATIM (passed, ~13-16us): (L@Y) + gate
// epilogue.  LDS 37,888 B.  DO NOT PERTURB.
// ===========================================================================
__global__ __launch_bounds__(512) void gcz_kernel(
    const float* __restrict__ L, const float* __restrict__ Y,
    const float* __restrict__ Hprev, const float* __restrict__ u,
    const float* __restrict__ Lx, const float* __restrict__ W2,
    const float* __restrict__ b2, const float* __restrict__ aw1,
    const float* __restrict__ ab1, float* __restrict__ Hnew,
    float* __restrict__ hs1, int t) {
    __shared__ __align__(16) union Buf {
        float Ht[2][32][H_];                              // 32768 B
        struct { float R[32][H_]; float Zb[16][H_]; } s;  // R unused here
    } bb;
    __shared__ __align__(16) float Lt[2][32][20];         // 5120 B

    const int tid = threadIdx.x;
    const int b = blockIdx.x & 15;
    const int m0 = (blockIdx.x >> 4) * 16;
    const float* __restrict__ Yb = Y + (size_t)b * NH;

    const int hrow = tid >> 5, hcol = (tid & 31) * 4;
    const int lm = tid >> 5, lk = tid & 31;

    {
        *(float4*)&bb.Ht[0][hrow][hcol] =
            *(const float4*)&Yb[(size_t)hrow * H_ + hcol];
        *(float4*)&bb.Ht[0][hrow + 16][hcol] =
            *(const float4*)&Yb[(size_t)(hrow + 16) * H_ + hcol];
        Lt[0][lk][lm] = L[(size_t)(m0 + lm) * N_ + lk];
    }
    __syncthreads();

    const int g = tid >> 6;
    const int l = tid & 63;
    const int ty = l >> 4;
    const int tx = l & 15;
    const int ma0 = ty * 4;
    const int ca0 = tx * 4, cb0 = 64 + tx * 4;

    float acc[4][2][4] = {};

    for (int kc = 0; kc < 16; ++kc) {
        const int bi = kc & 1, bj = bi ^ 1;
        float4 p0, p1;
        float pl;
        if (kc < 15) {
            const size_t kb = (size_t)(kc + 1) * 32;
            p0 = *(const float4*)&Yb[(kb + hrow) * H_ + hcol];
            p1 = *(const float4*)&Yb[(kb + hrow + 16) * H_ + hcol];
            pl = L[(size_t)(m0 + lm) * N_ + kb + lk];
        }
#pragma unroll
        for (int kk = 0; kk < 4; ++kk) {
            const int k = g * 4 + kk;
            const float4 la = *(const float4*)&Lt[bi][k][ma0];
            const float4 h0 = *(const float4*)&bb.Ht[bi][k][ca0];
            const float4 h1 = *(const float4*)&bb.Ht[bi][k][cb0];
            FMA4(acc[0][0], la.x, h0) FMA4(acc[0][1], la.x, h1)
            FMA4(acc[1][0], la.y, h0) FMA4(acc[1][1], la.y, h1)
            FMA4(acc[2][0], la.z, h0) FMA4(acc[2][1], la.z, h1)
            FMA4(acc[3][0], la.w, h0) FMA4(acc[3][1], la.w, h1)
        }
        if (kc < 15) {
            *(float4*)&bb.Ht[bj][hrow][hcol] = p0;
            *(float4*)&bb.Ht[bj][hrow + 16][hcol] = p1;
            Lt[bj][lk][lm] = pl;
        }
        __syncthreads();
    }

    for (int r = 0; r < 8; ++r) {
        if (g == r) {
#pragma unroll
            for (int i = 0; i < 4; ++i) {
#pragma unroll
                for (int v = 0; v < 2; ++v) {
                    const int c = v ? cb0 : ca0;
                    float4* zp = (float4*)&bb.s.Zb[ma0 + i][c];
                    if (r == 0) {
                        *zp = make_float4(acc[i][v][0], acc[i][v][1],
                                          acc[i][v][2], acc[i][v][3]);
                    } else {
                        float4 z = *zp;
                        *zp = make_float4(z.x + acc[i][v][0], z.y + acc[i][v][1],
                                          z.z + acc[i][v][2], z.w + acc[i][v][3]);
                    }
                }
            }
        }
        __syncthreads();
    }

    const int zr = tid >> 5;                       // 0..15
    const int zc = (tid & 31) * 4;                 // 0..124
    const float4 zv = *(const float4*)&bb.s.Zb[zr][zc];
    const float4 w0r = *(const float4*)&W2[zc];
    const float4 bbv = *(const float4*)&b2[zc];
    const float4 awv = *(const float4*)&aw1[zc];
    const float lx = Lx[((size_t)b * T_ + t) * N_ + m0 + zr];

    float c0 = tanhf(zv.x + lx * w0r.x + bbv.x);
    float c1 = tanhf(zv.y + lx * w0r.y + bbv.y);
    float c2 = tanhf(zv.z + lx * w0r.z + bbv.z);
    float c3 = tanhf(zv.w + lx * w0r.w + bbv.w);

    const size_t fl = (size_t)b * NH + (size_t)(m0 + zr) * H_ + zc;
    const float4 uv = *(const float4*)&u[fl];
    const float4 hp = *(const float4*)&Hprev[fl];
    const float h0 = uv.x * hp.x + (1.f - uv.x) * c0;
    const float h1 = uv.y * hp.y + (1.f - uv.y) * c1;
    const float h2 = uv.z * hp.z + (1.f - uv.z) * c2;
    const float h3 = uv.w * hp.w + (1.f - uv.w) * c3;
    *(float4*)&Hnew[fl] = make_float4(h0, h1, h2, h3);

    float part = h0 * awv.x + h1 * awv.y + h2 * awv.z + h3 * awv.w;
#pragma unroll
    for (int off = 16; off; off >>= 1) part += __shfl_xor(part, off);
    if ((tid & 31) == 0)
        hs1[((size_t)b * T_ + t) * N_ + m0 + zr] = part + ab1[0];
}

// ---------------------------------------------------------------------------
// beta[b,t] = softmax_t( (hs1@aw2+ab2) * (hs1@aw3+ab3) )
// ---------------------------------------------------------------------------
__global__ __launch_bounds__(64) void att_beta_kernel(
    const float* __restrict__ hs1, const float* __restrict__ aw2,
    const float* __restrict__ aw3, const float* __restrict__ ab2,
    const float* __restrict__ ab3, float* __restrict__ beta) {
    const int b = blockIdx.x;
    const int t = threadIdx.x;
    const float* __restrict__ row = hs1 + ((size_t)b * T_ + t) * N_;
    float f = 0.f, g = 0.f;
    for (int n = 0; n < N_; n += 4) {
        float4 hv = *(const float4*)&row[n];
        float4 w2v = *(const float4*)&aw2[n];
        float4 w3v = *(const float4*)&aw3[n];
        f += hv.x * w2v.x + hv.y * w2v.y + hv.z * w2v.z + hv.w * w2v.w;
        g += hv.x * w3v.x + hv.y * w3v.y + hv.z * w3v.z + hv.w * w3v.w;
    }
    f += ab2[0];
    g += ab3[0];
    float s = f * g;
    float mx = s;
    for (int off = 32; off; off >>= 1) mx = fmaxf(mx, __shfl_xor(mx, off));
    float e = expf(s - mx);
    float sum = e;
    for (int off = 32; off; off >>= 1) sum += __shfl_xor(sum, off);
    beta[b * T_ + t] = e / sum;
}

// ---------------------------------------------------------------------------
// out[b,p,n] = b_out[p] + sum_t beta[b,t]*hs1[b,t,n]*W_out[t,p]
// ---------------------------------------------------------------------------
__global__ __launch_bounds__(256) void att_out_kernel(
    const float* __restrict__ hs1, const float* __restrict__ beta,
    const float* __restrict__ Wout, const float* __restrict__ bout,
    float* __restrict__ out) {
    __shared__ float bs[T_];
    __shared__ float ws[T_][P_];
    const int b = blockIdx.x;
    const int tid = threadIdx.x;
    if (tid < T_) bs[tid] = beta[b * T_ + tid];
    for (int i = tid; i < T_ * P_; i += 256) ws[i / P_][i % P_] = Wout[i];
    __syncthreads();
    for (int nn = 0; nn < 2; ++nn) {
        const int n = tid + nn * 256;
        float acc[P_];
#pragma unroll
        for (int p = 0; p < P_; ++p) acc[p] = bout[p];
        for (int t = 0; t < T_; ++t) {
            float v = bs[t] * hs1[((size_t)b * T_ + t) * N_ + n];
#pragma unroll
            for (int p = 0; p < P_; ++p) acc[p] += v * ws[t][p];
        }
#pragma unroll
        for (int p = 0; p < P_; ++p) out[((size_t)b * P_ + p) * N_ + n] = acc[p];
    }
}

extern "C" void kernel_launch(void* const* d_in, const int* in_sizes, int n_in,
                              void* d_out, int out_size, void* d_ws, size_t ws_size,
                              hipStream_t stream) {
    const float* x = (const float*)d_in[0];
    const float* L = (const float*)d_in[1];
    const float* W1 = (const float*)d_in[2];
    const float* b1 = (const float*)d_in[3];
    const float* W2 = (const float*)d_in[4];
    const float* b2 = (const float*)d_in[5];
    const float* aw1 = (const float*)d_in[6];
    const float* aw2 = (const float*)d_in[7];
    const float* aw3 = (const float*)d_in[8];
    const float* ab1 = (const float*)d_in[9];
    const float* ab2 = (const float*)d_in[10];
    const float* ab3 = (const float*)d_in[11];
    const float* Wout = (const float*)d_in[12];
    const float* bout = (const float*)d_in[13];
    float* out = (float*)d_out;

    float* ws = (float*)d_ws;
    float* Lx = ws;                       // B*T*N
    float* hs1 = Lx + B_ * T_ * N_;       // B*T*N
    float* hb0 = hs1 + B_ * T_ * N_;      // B*N*H
    float* hb1 = hb0 + (size_t)B_ * NH;   // B*N*H
    float* u = hb1 + (size_t)B_ * NH;     // B*N*H
    float* Ybuf = u + (size_t)B_ * NH;    // B*N*H
    float* beta = Ybuf + (size_t)B_ * NH; // B*T
    (void)in_sizes; (void)n_in; (void)out_size; (void)ws_size;

    hipMemsetAsync(hb0, 0, (size_t)B_ * NH * sizeof(float), stream);
    lx_kernel<<<512, 512, 0, stream>>>(x, L, Lx);

    for (int t = 0; t < T_; ++t) {
        float* hp = (t & 1) ? hb1 : hb0;
        float* hn = (t & 1) ? hb0 : hb1;
        gc1y_kernel<<<1024, 512, 0, stream>>>(L, hp, Lx, W1, b1, W2, Ybuf, u, t);
        gcz_kernel<<<512, 512, 0, stream>>>(L, Ybuf, hp, u, Lx, W2, b2, aw1,
                                            ab1, hn, hs1, t);
    }
    att_beta_kernel<<<16, 64, 0, stream>>>(hs1, aw2, aw3, ab2, ab3, beta);
    att_out_kernel<<<16, 256, 0, stream>>>(hs1, beta, Wout, bout, out);
}

// Round 20
// 3548.655 us; speedup vs baseline: 1.4368x; 1.4368x over previous
//
#include <hip/hip_runtime.h>
#include <math.h>

#define B_ 16
#define T_ 64
#define N_ 512
#define H_ 128
#define P_ 12
#define NH 65536  // N_*H_

// ---------------------------------------------------------------------------
// Lx[b,t,m] = sum_n L[m,n] * x[b,t,n]   (L symmetric)
// ---------------------------------------------------------------------------
__global__ __launch_bounds__(512) void lx_kernel(const float* __restrict__ x,
                                                 const float* __restrict__ L,
                                                 float* __restrict__ Lx) {
    __shared__ __align__(16) float xs[2][N_];
    const int r0 = blockIdx.x * 2;
    const int tid = threadIdx.x;
    for (int j = 0; j < 2; ++j)
        xs[j][tid] = x[(size_t)(r0 + j) * N_ + tid];
    __syncthreads();
    float a0 = 0.f, a1 = 0.f;
    const int m = tid;
#pragma unroll 8
    for (int n = 0; n < N_; ++n) {
        float lv = L[(size_t)n * N_ + m];
        a0 += xs[0][n] * lv;
        a1 += xs[1][n] * lv;
    }
    Lx[(size_t)(r0 + 0) * N_ + m] = a0;
    Lx[(size_t)(r0 + 1) * N_ + m] = a1;
}

#define FMA4(dst, a, hv)                                                      \
    dst[0] += (a) * (hv).x; dst[1] += (a) * (hv).y;                           \
    dst[2] += (a) * (hv).z; dst[3] += (a) * (hv).w;

// ===========================================================================
// gc1y — FINAL (R21; session best: 3551/3614/3790 us across three runs).
// Phase 1: L@H with double-buffered Ht/Lt staging.  Phases 2/3 wave-sliced
// (wave w owns its own W columns; Zb/R pitch 132).  Wave-count increases
// were tried three ways (R25 bound-8: VGPR 32 + 115MB spill; R26 bound-6:
// VGPR 40 + spill; R27 slim body natural 64 VGPR: clean but 65us — overhead
// scales with block count faster than latency hiding improves).  4 waves/
// SIMD with fat tiles is the verified local optimum for this body.
// ===========================================================================
__global__ __launch_bounds__(512) void gc1y_kernel(
    const float* __restrict__ L, const float* __restrict__ Hprev,
    const float* __restrict__ Lx, const float* __restrict__ W1,
    const float* __restrict__ b1, const float* __restrict__ W2,
    float* __restrict__ Y, float* __restrict__ u, int t) {
    __shared__ __align__(16) union Buf {
        float Ht[2][32][H_];                                // 32768 B
        struct { float R[32][132]; float Zb[16][132]; } s;  // 25344 B
    } bb;
    __shared__ __align__(16) union LW {
        float Lt[2][32][20];   // 5120 B
        float Wt[16][260];     // 16640 B
    } sm;
    // total 49,408 B

    const int tid = threadIdx.x;
    const int b = blockIdx.x & 15;         // XCD-locality decode
    const int m0 = (blockIdx.x >> 4) * 16;
    const float* __restrict__ Hb = Hprev + (size_t)b * NH;

    const int hrow = tid >> 5, hcol = (tid & 31) * 4;
    const int lm = tid >> 5, lk = tid & 31;

    {
        *(float4*)&bb.Ht[0][hrow][hcol] =
            *(const float4*)&Hb[(size_t)hrow * H_ + hcol];
        *(float4*)&bb.Ht[0][hrow + 16][hcol] =
            *(const float4*)&Hb[(size_t)(hrow + 16) * H_ + hcol];
        sm.Lt[0][lk][lm] = L[(size_t)(m0 + lm) * N_ + lk];
    }
    __syncthreads();

    const int g = tid >> 6;
    const int l = tid & 63;
    const int ty = l >> 4;
    const int tx = l & 15;
    const int ma0 = ty * 4;
    const int ca0 = tx * 4, cb0 = 64 + tx * 4;

    float acc[4][2][4] = {};

    for (int kc = 0; kc < 16; ++kc) {
        const int bi = kc & 1, bj = bi ^ 1;
        float4 p0, p1;
        float pl;
        if (kc < 15) {
            const size_t kb = (size_t)(kc + 1) * 32;
            p0 = *(const float4*)&Hb[(kb + hrow) * H_ + hcol];
            p1 = *(const float4*)&Hb[(kb + hrow + 16) * H_ + hcol];
            pl = L[(size_t)(m0 + lm) * N_ + kb + lk];
        }
#pragma unroll
        for (int kk = 0; kk < 4; ++kk) {
            const int k = g * 4 + kk;
            const float4 la = *(const float4*)&sm.Lt[bi][k][ma0];
            const float4 h0 = *(const float4*)&bb.Ht[bi][k][ca0];
            const float4 h1 = *(const float4*)&bb.Ht[bi][k][cb0];
            FMA4(acc[0][0], la.x, h0) FMA4(acc[0][1], la.x, h1)
            FMA4(acc[1][0], la.y, h0) FMA4(acc[1][1], la.y, h1)
            FMA4(acc[2][0], la.z, h0) FMA4(acc[2][1], la.z, h1)
            FMA4(acc[3][0], la.w, h0) FMA4(acc[3][1], la.w, h1)
        }
        if (kc < 15) {
            *(float4*)&bb.Ht[bj][hrow][hcol] = p0;
            *(float4*)&bb.Ht[bj][hrow + 16][hcol] = p1;
            sm.Lt[bj][lk][lm] = pl;
        }
        __syncthreads();
    }

    for (int r = 0; r < 8; ++r) {
        if (g == r) {
#pragma unroll
            for (int i = 0; i < 4; ++i) {
#pragma unroll
                for (int v = 0; v < 2; ++v) {
                    const int c = v ? cb0 : ca0;
                    float4* zp = (float4*)&bb.s.Zb[ma0 + i][c];
                    if (r == 0) {
                        *zp = make_float4(acc[i][v][0], acc[i][v][1],
                                          acc[i][v][2], acc[i][v][3]);
                    } else {
                        float4 z = *zp;
                        *zp = make_float4(z.x + acc[i][v][0], z.y + acc[i][v][1],
                                          z.z + acc[i][v][2], z.w + acc[i][v][3]);
                    }
                }
            }
        }
        __syncthreads();
    }

    // ---- phase 2: ru = Zb @ W1[1:]  (wave-sliced cols: wave w -> w*32..+31)
    const int wv8 = tid >> 6;             // wave 0..7
    const int lr = l >> 3;                // row slot 0..7 (rows lr, lr+8)
    const int lc = wv8 * 32 + (l & 7) * 4; // col 0..252
    float a2[2][4] = {};
    const int wr = tid >> 5, wc = (tid & 31) * 4;

#pragma unroll 1
    for (int ck = 0; ck < 8; ++ck) {
        *(float4*)&sm.Wt[wr][wc] =
            *(const float4*)&W1[(size_t)(1 + ck * 16 + wr) * 256 + wc];
        *(float4*)&sm.Wt[wr][wc + 128] =
            *(const float4*)&W1[(size_t)(1 + ck * 16 + wr) * 256 + wc + 128];
        __syncthreads();
#pragma unroll
        for (int ch4 = 0; ch4 < 4; ++ch4) {
            const int cc = ck * 16 + ch4 * 4;
            const float4 z0v = *(const float4*)&bb.s.Zb[lr][cc];
            const float4 z1v = *(const float4*)&bb.s.Zb[lr + 8][cc];
            const float4 w0v = *(const float4*)&sm.Wt[ch4 * 4 + 0][lc];
            const float4 w1v = *(const float4*)&sm.Wt[ch4 * 4 + 1][lc];
            const float4 w2v = *(const float4*)&sm.Wt[ch4 * 4 + 2][lc];
            const float4 w3v = *(const float4*)&sm.Wt[ch4 * 4 + 3][lc];
            a2[0][0] += z0v.x * w0v.x + z0v.y * w1v.x + z0v.z * w2v.x + z0v.w * w3v.x;
            a2[0][1] += z0v.x * w0v.y + z0v.y * w1v.y + z0v.z * w2v.y + z0v.w * w3v.y;
            a2[0][2] += z0v.x * w0v.z + z0v.y * w1v.z + z0v.z * w2v.z + z0v.w * w3v.z;
            a2[0][3] += z0v.x * w0v.w + z0v.y * w1v.w + z0v.z * w2v.w + z0v.w * w3v.w;
            a2[1][0] += z1v.x * w0v.x + z1v.y * w1v.x + z1v.z * w2v.x + z1v.w * w3v.x;
            a2[1][1] += z1v.x * w0v.y + z1v.y * w1v.y + z1v.z * w2v.y + z1v.w * w3v.y;
            a2[1][2] += z1v.x * w0v.z + z1v.y * w1v.z + z1v.z * w2v.z + z1v.w * w3v.z;
            a2[1][3] += z1v.x * w0v.w + z1v.y * w1v.w + z1v.z * w2v.w + z1v.w * w3v.w;
        }
        __syncthreads();
    }

    const float4 w0r = *(const float4*)&W1[lc];
    const float4 bbv = *(const float4*)&b1[lc];
    const float* __restrict__ LxRow = Lx + ((size_t)b * T_ + t) * N_ + m0;
    const bool isR = (m0 < 256);

    if (isR) {
        // rh = sigmoid(v) * Hprev  -> bb.s.R (pitch 132)
#pragma unroll
        for (int i = 0; i < 2; ++i) {
            const int mi = lr + 8 * i;
            const float lx = LxRow[mi];
            float v0 = a2[i][0] + lx * w0r.x + bbv.x;
            float v1 = a2[i][1] + lx * w0r.y + bbv.y;
            float v2 = a2[i][2] + lx * w0r.z + bbv.z;
            float v3 = a2[i][3] + lx * w0r.w + bbv.w;
            float s0 = 1.f / (1.f + expf(-v0));
            float s1 = 1.f / (1.f + expf(-v1));
            float s2 = 1.f / (1.f + expf(-v2));
            float s3 = 1.f / (1.f + expf(-v3));
            const int fl = (m0 + mi) * 256 + lc;
            float4 hv = *(const float4*)&Hb[fl];
            *(float4*)&bb.s.R[2 * mi + (lc >> 7)][lc & 127] =
                make_float4(s0 * hv.x, s1 * hv.y, s2 * hv.z, s3 * hv.w);
        }
        __syncthreads();

        // ---- phase 3: Y rows 2m0..2m0+31 = R @ W2[1:]  (wave-sliced cols)
        const int pr = l >> 2;                 // 0..15 (rows pr, pr+16)
        const int pc = wv8 * 16 + (l & 3) * 4; // col 0..124
        float a3[2][4] = {};
#pragma unroll 1
        for (int ck = 0; ck < 8; ++ck) {
            *(float4*)&sm.Wt[wr][wc] =
                *(const float4*)&W2[(size_t)(1 + ck * 16 + wr) * H_ + wc];
            __syncthreads();
#pragma unroll
            for (int ch4 = 0; ch4 < 4; ++ch4) {
                const int cc = ck * 16 + ch4 * 4;
                const float4 z0v = *(const float4*)&bb.s.R[pr][cc];
                const float4 z1v = *(const float4*)&bb.s.R[pr + 16][cc];
                const float4 w0v = *(const float4*)&sm.Wt[ch4 * 4 + 0][pc];
                const float4 w1v = *(const float4*)&sm.Wt[ch4 * 4 + 1][pc];
                const float4 w2v = *(const float4*)&sm.Wt[ch4 * 4 + 2][pc];
                const float4 w3v = *(const float4*)&sm.Wt[ch4 * 4 + 3][pc];
                a3[0][0] += z0v.x * w0v.x + z0v.y * w1v.x + z0v.z * w2v.x + z0v.w * w3v.x;
                a3[0][1] += z0v.x * w0v.y + z0v.y * w1v.y + z0v.z * w2v.y + z0v.w * w3v.y;
                a3[0][2] += z0v.x * w0v.z + z0v.y * w1v.z + z0v.z * w2v.z + z0v.w * w3v.z;
                a3[0][3] += z0v.x * w0v.w + z0v.y * w1v.w + z0v.z * w2v.w + z0v.w * w3v.w;
                a3[1][0] += z1v.x * w0v.x + z1v.y * w1v.x + z1v.z * w2v.x + z1v.w * w3v.x;
                a3[1][1] += z1v.x * w0v.y + z1v.y * w1v.y + z1v.z * w2v.y + z1v.w * w3v.y;
                a3[1][2] += z1v.x * w0v.z + z1v.y * w1v.z + z1v.z * w2v.z + z1v.w * w3v.z;
                a3[1][3] += z1v.x * w0v.w + z1v.y * w1v.w + z1v.z * w2v.w + z1v.w * w3v.w;
            }
            __syncthreads();
        }
        float* __restrict__ Yb = Y + (size_t)b * NH;
        *(float4*)&Yb[(size_t)(2 * m0 + pr) * H_ + pc] =
            make_float4(a3[0][0], a3[0][1], a3[0][2], a3[0][3]);
        *(float4*)&Yb[(size_t)(2 * m0 + pr + 16) * H_ + pc] =
            make_float4(a3[1][0], a3[1][1], a3[1][2], a3[1][3]);
    } else {
        float* __restrict__ uB = u + (size_t)b * NH;
#pragma unroll
        for (int i = 0; i < 2; ++i) {
            const int mi = lr + 8 * i;
            const float lx = LxRow[mi];
            float v0 = a2[i][0] + lx * w0r.x + bbv.x;
            float v1 = a2[i][1] + lx * w0r.y + bbv.y;
            float v2 = a2[i][2] + lx * w0r.z + bbv.z;
            float v3 = a2[i][3] + lx * w0r.w + bbv.w;
            float s0 = 1.f / (1.f + expf(-v0));
            float s1 = 1.f / (1.f + expf(-v1));
            float s2 = 1.f / (1.f + expf(-v2));
            float s3 = 1.f / (1.f + expf(-v3));
            const int fl = (m0 + mi) * 256 + lc;
            *(float4*)&uB[fl - NH] = make_float4(s0, s1, s2, s3);
        }
    }
}

// ===========================================================================
// gcz_kernel — R18 version VERBATIM: (L@Y) + gate epilogue.  LDS 37,888 B.
// ===========================================================================
__global__ __launch_bounds__(512) void gcz_kernel(
    const float* __restrict__ L, const float* __restrict__ Y,
    const float* __restrict__ Hprev, const float* __restrict__ u,
    const float* __restrict__ Lx, const float* __restrict__ W2,
    const float* __restrict__ b2, const float* __restrict__ aw1,
    const float* __restrict__ ab1, float* __restrict__ Hnew,
    float* __restrict__ hs1, int t) {
    __shared__ __align__(16) union Buf {
        float Ht[2][32][H_];                              // 32768 B
        struct { float R[32][H_]; float Zb[16][H_]; } s;  // R unused here
    } bb;
    __shared__ __align__(16) float Lt[2][32][20];         // 5120 B

    const int tid = threadIdx.x;
    const int b = blockIdx.x & 15;
    const int m0 = (blockIdx.x >> 4) * 16;
    const float* __restrict__ Yb = Y + (size_t)b * NH;

    const int hrow = tid >> 5, hcol = (tid & 31) * 4;
    const int lm = tid >> 5, lk = tid & 31;

    {
        *(float4*)&bb.Ht[0][hrow][hcol] =
            *(const float4*)&Yb[(size_t)hrow * H_ + hcol];
        *(float4*)&bb.Ht[0][hrow + 16][hcol] =
            *(const float4*)&Yb[(size_t)(hrow + 16) * H_ + hcol];
        Lt[0][lk][lm] = L[(size_t)(m0 + lm) * N_ + lk];
    }
    __syncthreads();

    const int g = tid >> 6;
    const int l = tid & 63;
    const int ty = l >> 4;
    const int tx = l & 15;
    const int ma0 = ty * 4;
    const int ca0 = tx * 4, cb0 = 64 + tx * 4;

    float acc[4][2][4] = {};

    for (int kc = 0; kc < 16; ++kc) {
        const int bi = kc & 1, bj = bi ^ 1;
        float4 p0, p1;
        float pl;
        if (kc < 15) {
            const size_t kb = (size_t)(kc + 1) * 32;
            p0 = *(const float4*)&Yb[(kb + hrow) * H_ + hcol];
            p1 = *(const float4*)&Yb[(kb + hrow + 16) * H_ + hcol];
            pl = L[(size_t)(m0 + lm) * N_ + kb + lk];
        }
#pragma unroll
        for (int kk = 0; kk < 4; ++kk) {
            const int k = g * 4 + kk;
            const float4 la = *(const float4*)&Lt[bi][k][ma0];
            const float4 h0 = *(const float4*)&bb.Ht[bi][k][ca0];
            const float4 h1 = *(const float4*)&bb.Ht[bi][k][cb0];
            FMA4(acc[0][0], la.x, h0) FMA4(acc[0][1], la.x, h1)
            FMA4(acc[1][0], la.y, h0) FMA4(acc[1][1], la.y, h1)
            FMA4(acc[2][0], la.z, h0) FMA4(acc[2][1], la.z, h1)
            FMA4(acc[3][0], la.w, h0) FMA4(acc[3][1], la.w, h1)
        }
        if (kc < 15) {
            *(float4*)&bb.Ht[bj][hrow][hcol] = p0;
            *(float4*)&bb.Ht[bj][hrow + 16][hcol] = p1;
            Lt[bj][lk][lm] = pl;
        }
        __syncthreads();
    }

    for (int r = 0; r < 8; ++r) {
        if (g == r) {
#pragma unroll
            for (int i = 0; i < 4; ++i) {
#pragma unroll
                for (int v = 0; v < 2; ++v) {
                    const int c = v ? cb0 : ca0;
                    float4* zp = (float4*)&bb.s.Zb[ma0 + i][c];
                    if (r == 0) {
                        *zp = make_float4(acc[i][v][0], acc[i][v][1],
                                          acc[i][v][2], acc[i][v][3]);
                    } else {
                        float4 z = *zp;
                        *zp = make_float4(z.x + acc[i][v][0], z.y + acc[i][v][1],
                                          z.z + acc[i][v][2], z.w + acc[i][v][3]);
                    }
                }
            }
        }
        __syncthreads();
    }

    const int zr = tid >> 5;                       // 0..15
    const int zc = (tid & 31) * 4;                 // 0..124
    const float4 zv = *(const float4*)&bb.s.Zb[zr][zc];
    const float4 w0r = *(const float4*)&W2[zc];
    const float4 bbv = *(const float4*)&b2[zc];
    const float4 awv = *(const float4*)&aw1[zc];
    const float lx = Lx[((size_t)b * T_ + t) * N_ + m0 + zr];

    float c0 = tanhf(zv.x + lx * w0r.x + bbv.x);
    float c1 = tanhf(zv.y + lx * w0r.y + bbv.y);
    float c2 = tanhf(zv.z + lx * w0r.z + bbv.z);
    float c3 = tanhf(zv.w + lx * w0r.w + bbv.w);

    const size_t fl = (size_t)b * NH + (size_t)(m0 + zr) * H_ + zc;
    const float4 uv = *(const float4*)&u[fl];
    const float4 hp = *(const float4*)&Hprev[fl];
    const float h0 = uv.x * hp.x + (1.f - uv.x) * c0;
    const float h1 = uv.y * hp.y + (1.f - uv.y) * c1;
    const float h2 = uv.z * hp.z + (1.f - uv.z) * c2;
    const float h3 = uv.w * hp.w + (1.f - uv.w) * c3;
    *(float4*)&Hnew[fl] = make_float4(h0, h1, h2, h3);

    float part = h0 * awv.x + h1 * awv.y + h2 * awv.z + h3 * awv.w;
#pragma unroll
    for (int off = 16; off; off >>= 1) part += __shfl_xor(part, off);
    if ((tid & 31) == 0)
        hs1[((size_t)b * T_ + t) * N_ + m0 + zr] = part + ab1[0];
}

// ---------------------------------------------------------------------------
// beta[b,t] = softmax_t( (hs1@aw2+ab2) * (hs1@aw3+ab3) )
// ---------------------------------------------------------------------------
__global__ __launch_bounds__(64) void att_beta_kernel(
    const float* __restrict__ hs1, const float* __restrict__ aw2,
    const float* __restrict__ aw3, const float* __restrict__ ab2,
    const float* __restrict__ ab3, float* __restrict__ beta) {
    const int b = blockIdx.x;
    const int t = threadIdx.x;
    const float* __restrict__ row = hs1 + ((size_t)b * T_ + t) * N_;
    float f = 0.f, g = 0.f;
    for (int n = 0; n < N_; n += 4) {
        float4 hv = *(const float4*)&row[n];
        float4 w2v = *(const float4*)&aw2[n];
        float4 w3v = *(const float4*)&aw3[n];
        f += hv.x * w2v.x + hv.y * w2v.y + hv.z * w2v.z + hv.w * w2v.w;
        g += hv.x * w3v.x + hv.y * w3v.y + hv.z * w3v.z + hv.w * w3v.w;
    }
    f += ab2[0];
    g += ab3[0];
    float s = f * g;
    float mx = s;
    for (int off = 32; off; off >>= 1) mx = fmaxf(mx, __shfl_xor(mx, off));
    float e = expf(s - mx);
    float sum = e;
    for (int off = 32; off; off >>= 1) sum += __shfl_xor(sum, off);
    beta[b * T_ + t] = e / sum;
}

// ---------------------------------------------------------------------------
// out[b,p,n] = b_out[p] + sum_t beta[b,t]*hs1[b,t,n]*W_out[t,p]
// ---------------------------------------------------------------------------
__global__ __launch_bounds__(256) void att_out_kernel(
    const float* __restrict__ hs1, const float* __restrict__ beta,
    const float* __restrict__ Wout, const float* __restrict__ bout,
    float* __restrict__ out) {
    __shared__ float bs[T_];
    __shared__ float ws[T_][P_];
    const int b = blockIdx.x;
    const int tid = threadIdx.x;
    if (tid < T_) bs[tid] = beta[b * T_ + tid];
    for (int i = tid; i < T_ * P_; i += 256) ws[i / P_][i % P_] = Wout[i];
    __syncthreads();
    for (int nn = 0; nn < 2; ++nn) {
        const int n = tid + nn * 256;
        float acc[P_];
#pragma unroll
        for (int p = 0; p < P_; ++p) acc[p] = bout[p];
        for (int t = 0; t < T_; ++t) {
            float v = bs[t] * hs1[((size_t)b * T_ + t) * N_ + n];
#pragma unroll
            for (int p = 0; p < P_; ++p) acc[p] += v * ws[t][p];
        }
#pragma unroll
        for (int p = 0; p < P_; ++p) out[((size_t)b * P_ + p) * N_ + n] = acc[p];
    }
}

extern "C" void kernel_launch(void* const* d_in, const int* in_sizes, int n_in,
                              void* d_out, int out_size, void* d_ws, size_t ws_size,
                              hipStream_t stream) {
    const float* x = (const float*)d_in[0];
    const float* L = (const float*)d_in[1];
    const float* W1 = (const float*)d_in[2];
    const float* b1 = (const float*)d_in[3];
    const float* W2 = (const float*)d_in[4];
    const float* b2 = (const float*)d_in[5];
    const float* aw1 = (const float*)d_in[6];
    const float* aw2 = (const float*)d_in[7];
    const float* aw3 = (const float*)d_in[8];
    const float* ab1 = (const float*)d_in[9];
    const float* ab2 = (const float*)d_in[10];
    const float* ab3 = (const float*)d_in[11];
    const float* Wout = (const float*)d_in[12];
    const float* bout = (const float*)d_in[13];
    float* out = (float*)d_out;

    float* ws = (float*)d_ws;
    float* Lx = ws;                       // B*T*N
    float* hs1 = Lx + B_ * T_ * N_;       // B*T*N
    float* hb0 = hs1 + B_ * T_ * N_;      // B*N*H
    float* hb1 = hb0 + (size_t)B_ * NH;   // B*N*H
    float* u = hb1 + (size_t)B_ * NH;     // B*N*H
    float* Ybuf = u + (size_t)B_ * NH;    // B*N*H
    float* beta = Ybuf + (size_t)B_ * NH; // B*T
    (void)in_sizes; (void)n_in; (void)out_size; (void)ws_size;

    hipMemsetAsync(hb0, 0, (size_t)B_ * NH * sizeof(float), stream);
    lx_kernel<<<512, 512, 0, stream>>>(x, L, Lx);

    for (int t = 0; t < T_; ++t) {
        float* hp = (t & 1) ? hb1 : hb0;
        float* hn = (t & 1) ? hb0 : hb1;
        gc1y_kernel<<<512, 512, 0, stream>>>(L, hp, Lx, W1, b1, W2, Ybuf, u, t);
        gcz_kernel<<<512, 512, 0, stream>>>(L, Ybuf, hp, u, Lx, W2, b2, aw1,
                                            ab1, hn, hs1, t);
    }
    att_beta_kernel<<<16, 64, 0, stream>>>(hs1, aw2, aw3, ab2, ab3, beta);
    att_out_kernel<<<16, 256, 0, stream>>>(hs1, beta, Wout, bout, out);
}